// Round 18
// baseline (97.572 us; speedup 1.0000x reference)
//
#include <hip/hip_runtime.h>
#include <hip/hip_bf16.h>
#include <math.h>

#define BN 32
#define XLEN 1024
#define COLS 512
#define ROWS (BN * XLEN)   // 32768
#define STAB 1e-15

typedef float v2f __attribute__((ext_vector_type(2)));

// hardware transcendentals via AMDGCN builtins (glibc-collision-free):
//   HW_EXP2(x) = v_exp_f32 = 2^x ;  HW_LOG2(x) = v_log_f32 = log2(x)
#define HW_EXP2(x) __builtin_amdgcn_exp2f(x)
#define HW_LOG2(x) __builtin_amdgcn_logf(x)
#define HW_RCP(x)  __builtin_amdgcn_rcpf(x)

// ---------------------------------------------------------------------------
// FUSED kernel: gaus-fit phase (identical numerics to round 16, which passed
// at absmax 2048) + per-batch tridiagonal PCR solve, fused via a
// batch-completion atomic:
//   - grid 2048 blocks of 256 threads; block b computes rows 16b..16b+15.
//   - batch = b >> 6 (64 blocks per batch of 1024 rows).
//   - after writing mu/sigma: __syncthreads (drains stores), thread-0
//     device-scope release fence + atomicAdd on cnt[batch]. The LAST arriving
//     block (old == 63) acquires and runs the batch's PCR solve with its 256
//     threads (4 elements each). No block ever waits -> no deadlock; the
//     solve result is independent of arrival order -> deterministic output.
//   - PCR: single-buffer LDS A,B,C,D (16 KB/block; 8 blocks/CU still fit),
//     neighbor reciprocals via v_rcp_f32 (1-ulp, f32-solve class), 10 steps.
// PRECISION NOTE (round-14 lesson): the fit formula amplifies relative error
// on the row sums; per-lane f32 accumulation is tolerated but the cross-lane
// reduction tree MUST be f64.
// ---------------------------------------------------------------------------
__global__ __launch_bounds__(256, 8) void fused_kernel(
    const float* __restrict__ x, const float* __restrict__ w_comp,
    float* __restrict__ mu_ws, float* __restrict__ sig_ws,
    unsigned* __restrict__ cnt, float* __restrict__ out) {
  __shared__ float As[XLEN], Bs[XLEN], Cs[XLEN], Ds[XLEN];
  __shared__ int go;

  const int lane = threadIdx.x & 63;
  const int wid  = threadIdx.x >> 6;   // wave 0..3 in block
  const int sub  = lane & 15;          // lane within row-group
  const int row  = blockIdx.x * 16 + wid * 4 + (lane >> 4);

  // ---------------- gaus phase (byte-identical numerics to round 16) -------
  const v2f* rp2 = (const v2f*)(x + (size_t)row * COLS);
  v2f ve[16];
#pragma unroll
  for (int j = 0; j < 8; ++j) {
    ve[2 * j]     = rp2[32 * j + 2 * sub];
    ve[2 * j + 1] = rp2[32 * j + 2 * sub + 1];
  }

  v2f mx2 = ve[0], xn2 = ve[0];
#pragma unroll
  for (int k = 1; k < 16; ++k) {
    mx2 = __builtin_elementwise_max(mx2, ve[k]);
    xn2 = __builtin_elementwise_min(xn2, ve[k]);
  }
  float mx = fmaxf(mx2.x, mx2.y);
  float xn = fminf(xn2.x, xn2.y);
#pragma unroll
  for (int m = 8; m >= 1; m >>= 1) {
    mx = fmaxf(mx, __shfl_xor(mx, m, 64));
    xn = fminf(xn, __shfl_xor(xn, m, 64));
  }

  const float LOG2E = 1.44269504089f;
  const float mxs = mx * LOG2E;
  const v2f L2E2 = {LOG2E, LOG2E};
  const v2f NMXS = {-mxs, -mxs};
  v2f S2a = {0.0f, 0.0f}, S2b = {0.0f, 0.0f};
#pragma unroll
  for (int k = 0; k < 16; k += 2) {
    const v2f xs0 = __builtin_elementwise_fma(ve[k], L2E2, NMXS);
    const v2f xs1 = __builtin_elementwise_fma(ve[k + 1], L2E2, NMXS);
    ve[k].x     = HW_EXP2(xs0.x);
    ve[k].y     = HW_EXP2(xs0.y);
    ve[k + 1].x = HW_EXP2(xs1.x);
    ve[k + 1].y = HW_EXP2(xs1.y);
    S2a += ve[k];
    S2b += ve[k + 1];
  }
  const v2f S2 = S2a + S2b;
  float S = S2.x + S2.y;
#pragma unroll
  for (int m = 8; m >= 1; m >>= 1) S += __shfl_xor(S, m, 64);

  const float invS   = 1.0f / S;
  const float emin   = HW_EXP2(fmaf(xn, LOG2E, -mxs));  // == min over e
  const float pmin   = emin * invS;
  const float pmax   = invS;              // emax = exp(0) = 1 exactly
  const float invden = 1.0f / (pmax - pmin);
  const float CA     = invS * invden;
  const float CB     = fmaf(-pmin, invden, 0.001f);
  const v2f CA2 = {CA, CA}, CB2 = {CB, CB};

  const float bb = (float)(4 * sub) * (1.0f / 512.0f);
  v2f u0 = {0, 0}, u1 = {0, 0}, u2 = {0, 0}, u3 = {0, 0}, u4 = {0, 0};
  v2f w0 = {0, 0}, w1 = {0, 0}, w2 = {0, 0};

#define GF_PAIR(j, h)                                                         \
  {                                                                           \
    const int   k   = 2 * (j) + (h);                                          \
    const float off = (float)(64 * (j) + 2 * (h)) * (1.0f / 512.0f);          \
    const v2f xh = {bb + off, bb + off + 0.001953125f};                       \
    const v2f pn = __builtin_elementwise_fma(ve[k], CA2, CB2);                \
    v2f l2;                                                                   \
    l2.x = HW_LOG2(pn.x);                                                     \
    l2.y = HW_LOG2(pn.y);                                                     \
    const v2f y2  = pn * pn;                                                  \
    const v2f y2l = y2 * l2;                                                  \
    const v2f x2  = xh * xh;                                                  \
    const v2f x3  = x2 * xh;                                                  \
    const v2f x4  = x2 * x2;                                                  \
    u0 += y2;                                                                 \
    u1 = __builtin_elementwise_fma(xh, y2, u1);                               \
    u2 = __builtin_elementwise_fma(x2, y2, u2);                               \
    u3 = __builtin_elementwise_fma(x3, y2, u3);                               \
    u4 = __builtin_elementwise_fma(x4, y2, u4);                               \
    w0 += y2l;                                                                \
    w1 = __builtin_elementwise_fma(xh, y2l, w1);                              \
    w2 = __builtin_elementwise_fma(x2, y2l, w2);                              \
  }

#pragma unroll
  for (int j = 0; j < 8; ++j) {
    GF_PAIR(j, 0)
    GF_PAIR(j, 1)
  }
#undef GF_PAIR

  // per-lane exact f64 hadd, then 4-step f64 butterfly (f64 REQUIRED)
  double d0 = (double)u0.x + (double)u0.y;
  double d1 = (double)u1.x + (double)u1.y;
  double d2 = (double)u2.x + (double)u2.y;
  double d3 = (double)u3.x + (double)u3.y;
  double d4 = (double)u4.x + (double)u4.y;
  double e0 = (double)w0.x + (double)w0.y;
  double e1 = (double)w1.x + (double)w1.y;
  double e2 = (double)w2.x + (double)w2.y;
#pragma unroll
  for (int m = 8; m >= 1; m >>= 1) {
    d0 += __shfl_xor(d0, m, 64);
    d1 += __shfl_xor(d1, m, 64);
    d2 += __shfl_xor(d2, m, 64);
    d3 += __shfl_xor(d3, m, 64);
    d4 += __shfl_xor(d4, m, 64);
    e0 += __shfl_xor(e0, m, 64);
    e1 += __shfl_xor(e1, m, 64);
    e2 += __shfl_xor(e2, m, 64);
  }

  if (sub == 0) {   // lanes 0,16,32,48 — one per row
    const double LN2D = 0.6931471805599453;
    const double s_y2    = d0;
    const double s_xy2   = d1 * 512.0;
    const double s_x2y2  = d2 * 262144.0;            // 512^2
    const double s_x3y2  = d3 * 134217728.0;         // 512^3
    const double s_x4y2  = d4 * 68719476736.0;       // 512^4
    const double s_y2l   = e0 * LN2D;
    const double s_xy2l  = (e1 * 512.0) * LN2D;
    const double s_x2y2l = (e2 * 262144.0) * LN2D;
    const double A2 = s_x2y2 * s_x2y2;
    double b_num = A2 * s_xy2l - s_y2 * s_x4y2 * s_xy2l
                 + s_xy2 * s_x4y2 * s_y2l + s_y2 * s_x3y2 * s_x2y2l
                 - s_x2y2 * s_x3y2 * s_y2l - s_xy2 * s_x2y2 * s_x2y2l;
    double c_num = s_x2y2l * s_xy2 * s_xy2 - s_xy2l * s_xy2 * s_x2y2
                 - s_x3y2 * s_y2l * s_xy2 + s_y2l * A2
                 - s_y2 * s_x2y2l * s_x2y2 + s_y2 * s_x3y2 * s_xy2l;
    if (fabs(c_num) < STAB) {
      c_num = (c_num > 0.0) ? STAB : ((c_num < 0.0) ? -STAB : 0.0);
    }
    const double mu = -b_num / (2.0 * c_num);
    const double c_din = s_x4y2 * s_xy2 * s_xy2
                       - 2.0 * s_xy2 * s_x2y2 * s_x3y2 + s_x2y2 * A2
                       - s_y2 * s_x4y2 * s_x2y2 + s_y2 * s_x3y2 * s_x3y2;
    double sigma = -0.5 * c_din / c_num;
    if (sigma < 1.0) sigma = 1.0;  // NaN stays NaN, matching jnp.where
    mu_ws[row]  = (float)mu;
    sig_ws[row] = (float)sigma;
  }

  // ---------------- completion detect ----------------
  const int batch = blockIdx.x >> 6;   // 64 blocks per batch
  __syncthreads();                     // drains this block's stores (vmcnt 0)
  if (threadIdx.x == 0) {
    __threadfence();                   // device-scope release (L2 writeback)
    go = (atomicAdd(&cnt[batch], 1u) == 63u) ? 1 : 0;
  }
  __syncthreads();
  if (!go) return;                     // uniform across block
  __threadfence();                     // acquire: invalidate stale caches

  // ---------------- PCR phase: 256 threads x 4 elements, f32 --------------
  const int base = batch * XLEN;
  const float w = w_comp[0];
  const float offf = -2.0f * w;
  const int t = threadIdx.x;
#pragma unroll
  for (int q = 0; q < 4; ++q) {
    const int i = t + 256 * q;
    const float sr = 1.0f / sig_ws[base + i];     // f32, matches reference
    const float mainw = (i == 0 || i == XLEN - 1) ? (2.0f * w) : (4.0f * w);
    As[i] = (i == 0) ? 0.0f : offf;
    Cs[i] = (i == XLEN - 1) ? 0.0f : offf;
    Bs[i] = mainw + sr;
    Ds[i] = mu_ws[base + i] * sr;
  }
  __syncthreads();

  for (int s = 1; s < XLEN; s <<= 1) {
    float na[4], nb[4], nc[4], nd[4];
#pragma unroll
    for (int q = 0; q < 4; ++q) {
      const int i = t + 256 * q;
      const float ai = As[i], bi = Bs[i], ci = Cs[i], di = Ds[i];
      float am = 0.0f, cm = 0.0f, dm = 0.0f, rm = 0.0f;
      float ap = 0.0f, cp = 0.0f, dp = 0.0f, rp = 0.0f;
      if (i >= s) {
        am = As[i - s]; cm = Cs[i - s]; dm = Ds[i - s]; rm = HW_RCP(Bs[i - s]);
      }
      if (i + s < XLEN) {
        ap = As[i + s]; cp = Cs[i + s]; dp = Ds[i + s]; rp = HW_RCP(Bs[i + s]);
      }
      const float k1 = ai * rm;   // rm/rp are 0 when guarded out
      const float k2 = ci * rp;
      nb[q] = bi - k1 * cm - k2 * ap;
      nd[q] = di - k1 * dm - k2 * dp;
      na[q] = -k1 * am;
      nc[q] = -k2 * cp;
    }
    __syncthreads();
#pragma unroll
    for (int q = 0; q < 4; ++q) {
      const int i = t + 256 * q;
      As[i] = na[q]; Bs[i] = nb[q]; Cs[i] = nc[q]; Ds[i] = nd[q];
    }
    __syncthreads();
  }

#pragma unroll
  for (int q = 0; q < 4; ++q) {
    const int i = t + 256 * q;
    out[base + i] = Ds[i] / Bs[i];
  }
}

extern "C" void kernel_launch(void* const* d_in, const int* in_sizes, int n_in,
                              void* d_out, int out_size, void* d_ws, size_t ws_size,
                              hipStream_t stream) {
  const float* x      = (const float*)d_in[0];
  const float* w_comp = (const float*)d_in[1];
  float* out = (float*)d_out;

  float* mu_ws  = (float*)d_ws;
  float* sig_ws = mu_ws + ROWS;
  unsigned* cnt = (unsigned*)(sig_ws + ROWS);

  // d_ws is poisoned 0xAA once before timing and never re-poisoned; the
  // batch counters must start at 0 every call (deterministic re-runs).
  hipMemsetAsync((void*)cnt, 0, BN * sizeof(unsigned), stream);
  fused_kernel<<<ROWS / 16, 256, 0, stream>>>(x, w_comp, mu_ws, sig_ws, cnt, out);
}

// Round 19
// 25.380 us; speedup vs baseline: 3.8444x; 3.8444x over previous
//
#include <hip/hip_runtime.h>
#include <hip/hip_bf16.h>
#include <math.h>

#define BN 32
#define XLEN 1024
#define COLS 512
#define ROWS (BN * XLEN)   // 32768
#define STAB 1e-15

typedef float v2f __attribute__((ext_vector_type(2)));

// hardware transcendentals via AMDGCN builtins (glibc-collision-free):
//   HW_EXP2(x) = v_exp_f32 = 2^x ;  HW_LOG2(x) = v_log_f32 = log2(x)
#define HW_EXP2(x) __builtin_amdgcn_exp2f(x)
#define HW_LOG2(x) __builtin_amdgcn_logf(x)
#define HW_RCP(x)  __builtin_amdgcn_rcpf(x)

// ---------------------------------------------------------------------------
// Kernel 1: softmax (f32) -> min-max normalize (f32) -> weighted Gaussian fit.
// EXACTLY the round-13 configuration (best measured: 25.64 us, absmax 2048):
// 4 rows per wave, 16 lanes per row, 32 columns per lane (16 packed pairs);
// 4 waves per 256-thread block, grid 2048; no min-waves pin (neutral).
// float2 arithmetic -> packed dual-f32 VALU (v_pk_fma_f32 etc.).
// PRECISION NOTE (round-14 lesson): the closed-form fit formula amplifies
// relative error on the row sums by a large condition number. Per-lane f32
// accumulation is tolerated (noise partially cancels), but the cross-lane
// reduction tree MUST be f64.
// FUSION NOTE (round-18 lesson): fusing PCR into this kernel collapses
// regalloc to 32 VGPR and spills ve[16] to scratch (8.7 MB spill writes,
// 4x slowdown). Keep the two kernels separate.
//   e = exp2(fma(x,log2e,-mxs)); pn = fma(e,CA,CB); l2 = v_log_f32(pn);
//   xh from compile-time-exact constants; ln2 folded into the f64 log-sums;
//   verbatim f64 closed form + STAB/sigma clamps.
// ---------------------------------------------------------------------------
__global__ __launch_bounds__(256) void gaus_fit_kernel(
    const float* __restrict__ x, float* __restrict__ mu_out,
    float* __restrict__ sig_out) {
  const int lane = threadIdx.x & 63;
  const int wid  = threadIdx.x >> 6;   // wave 0..3 in block
  const int sub  = lane & 15;          // lane within row-group
  const int row  = blockIdx.x * 16 + wid * 4 + (lane >> 4);

  // Each lane: 16 v2f loads (adjacent pairs merge to dwordx4); pair k=2j+h
  // covers cols 64*j + 4*sub + {2h, 2h+1}.
  const v2f* rp2 = (const v2f*)(x + (size_t)row * COLS);
  v2f ve[16];
#pragma unroll
  for (int j = 0; j < 8; ++j) {
    ve[2 * j]     = rp2[32 * j + 2 * sub];
    ve[2 * j + 1] = rp2[32 * j + 2 * sub + 1];
  }

  // packed min/max of raw x, then component + 4-step butterfly reduce
  v2f mx2 = ve[0], xn2 = ve[0];
#pragma unroll
  for (int k = 1; k < 16; ++k) {
    mx2 = __builtin_elementwise_max(mx2, ve[k]);
    xn2 = __builtin_elementwise_min(xn2, ve[k]);
  }
  float mx = fmaxf(mx2.x, mx2.y);
  float xn = fminf(xn2.x, xn2.y);
#pragma unroll
  for (int m = 8; m >= 1; m >>= 1) {
    mx = fmaxf(mx, __shfl_xor(mx, m, 64));
    xn = fminf(xn, __shfl_xor(xn, m, 64));
  }

  // pass A: e = exp2(fma(x, log2e, -mxs)) overwrites ve in place; packed sum
  const float LOG2E = 1.44269504089f;
  const float mxs = mx * LOG2E;
  const v2f L2E2 = {LOG2E, LOG2E};
  const v2f NMXS = {-mxs, -mxs};
  v2f S2a = {0.0f, 0.0f}, S2b = {0.0f, 0.0f};
#pragma unroll
  for (int k = 0; k < 16; k += 2) {
    const v2f xs0 = __builtin_elementwise_fma(ve[k], L2E2, NMXS);
    const v2f xs1 = __builtin_elementwise_fma(ve[k + 1], L2E2, NMXS);
    ve[k].x     = HW_EXP2(xs0.x);
    ve[k].y     = HW_EXP2(xs0.y);
    ve[k + 1].x = HW_EXP2(xs1.x);
    ve[k + 1].y = HW_EXP2(xs1.y);
    S2a += ve[k];
    S2b += ve[k + 1];
  }
  const v2f S2 = S2a + S2b;
  float S = S2.x + S2.y;
#pragma unroll
  for (int m = 8; m >= 1; m >>= 1) S += __shfl_xor(S, m, 64);

  const float invS   = 1.0f / S;
  const float emin   = HW_EXP2(fmaf(xn, LOG2E, -mxs));  // == min over e
  const float pmin   = emin * invS;
  const float pmax   = invS;              // emax = exp(0) = 1 exactly
  const float invden = 1.0f / (pmax - pmin);
  const float CA     = invS * invden;
  const float CB     = fmaf(-pmin, invden, 0.001f);
  const v2f CA2 = {CA, CA}, CB2 = {CB, CB};

  // pass B: packed f32 moment accumulation with raw log2.
  // xh per pair = bb + compile-time-constant offset (exact): no serial chain.
  const float bb = (float)(4 * sub) * (1.0f / 512.0f);
  v2f u0 = {0, 0}, u1 = {0, 0}, u2 = {0, 0}, u3 = {0, 0}, u4 = {0, 0};
  v2f w0 = {0, 0}, w1 = {0, 0}, w2 = {0, 0};

#define GF_PAIR(j, h)                                                         \
  {                                                                           \
    const int   k   = 2 * (j) + (h);                                          \
    const float off = (float)(64 * (j) + 2 * (h)) * (1.0f / 512.0f);          \
    const v2f xh = {bb + off, bb + off + 0.001953125f};                       \
    const v2f pn = __builtin_elementwise_fma(ve[k], CA2, CB2);                \
    v2f l2;                                                                   \
    l2.x = HW_LOG2(pn.x);                                                     \
    l2.y = HW_LOG2(pn.y);                                                     \
    const v2f y2  = pn * pn;                                                  \
    const v2f y2l = y2 * l2;                                                  \
    const v2f x2  = xh * xh;                                                  \
    const v2f x3  = x2 * xh;                                                  \
    const v2f x4  = x2 * x2;                                                  \
    u0 += y2;                                                                 \
    u1 = __builtin_elementwise_fma(xh, y2, u1);                               \
    u2 = __builtin_elementwise_fma(x2, y2, u2);                               \
    u3 = __builtin_elementwise_fma(x3, y2, u3);                               \
    u4 = __builtin_elementwise_fma(x4, y2, u4);                               \
    w0 += y2l;                                                                \
    w1 = __builtin_elementwise_fma(xh, y2l, w1);                              \
    w2 = __builtin_elementwise_fma(x2, y2l, w2);                              \
  }

#pragma unroll
  for (int j = 0; j < 8; ++j) {
    GF_PAIR(j, 0)
    GF_PAIR(j, 1)
  }
#undef GF_PAIR

  // per-lane exact f64 hadd of packed sums, then 4-step f64 butterfly
  // (f64 REQUIRED here — see precision note above)
  double d0 = (double)u0.x + (double)u0.y;
  double d1 = (double)u1.x + (double)u1.y;
  double d2 = (double)u2.x + (double)u2.y;
  double d3 = (double)u3.x + (double)u3.y;
  double d4 = (double)u4.x + (double)u4.y;
  double e0 = (double)w0.x + (double)w0.y;
  double e1 = (double)w1.x + (double)w1.y;
  double e2 = (double)w2.x + (double)w2.y;
#pragma unroll
  for (int m = 8; m >= 1; m >>= 1) {
    d0 += __shfl_xor(d0, m, 64);
    d1 += __shfl_xor(d1, m, 64);
    d2 += __shfl_xor(d2, m, 64);
    d3 += __shfl_xor(d3, m, 64);
    d4 += __shfl_xor(d4, m, 64);
    e0 += __shfl_xor(e0, m, 64);
    e1 += __shfl_xor(e1, m, 64);
    e2 += __shfl_xor(e2, m, 64);
  }

  if (sub == 0) {   // lanes 0,16,32,48 — one per row
    const double LN2D = 0.6931471805599453;
    // unscale by exact 512^k; apply ln2 to the log2-sums (one rounding each)
    const double s_y2    = d0;
    const double s_xy2   = d1 * 512.0;
    const double s_x2y2  = d2 * 262144.0;            // 512^2
    const double s_x3y2  = d3 * 134217728.0;         // 512^3
    const double s_x4y2  = d4 * 68719476736.0;       // 512^4
    const double s_y2l   = e0 * LN2D;
    const double s_xy2l  = (e1 * 512.0) * LN2D;
    const double s_x2y2l = (e2 * 262144.0) * LN2D;
    const double A2 = s_x2y2 * s_x2y2;
    double b_num = A2 * s_xy2l - s_y2 * s_x4y2 * s_xy2l
                 + s_xy2 * s_x4y2 * s_y2l + s_y2 * s_x3y2 * s_x2y2l
                 - s_x2y2 * s_x3y2 * s_y2l - s_xy2 * s_x2y2 * s_x2y2l;
    double c_num = s_x2y2l * s_xy2 * s_xy2 - s_xy2l * s_xy2 * s_x2y2
                 - s_x3y2 * s_y2l * s_xy2 + s_y2l * A2
                 - s_y2 * s_x2y2l * s_x2y2 + s_y2 * s_x3y2 * s_xy2l;
    if (fabs(c_num) < STAB) {
      c_num = (c_num > 0.0) ? STAB : ((c_num < 0.0) ? -STAB : 0.0);
    }
    const double mu = -b_num / (2.0 * c_num);
    const double c_din = s_x4y2 * s_xy2 * s_xy2
                       - 2.0 * s_xy2 * s_x2y2 * s_x3y2 + s_x2y2 * A2
                       - s_y2 * s_x4y2 * s_x2y2 + s_y2 * s_x3y2 * s_x3y2;
    double sigma = -0.5 * c_din / c_num;
    if (sigma < 1.0) sigma = 1.0;  // NaN stays NaN, matching jnp.where
    mu_out[row]  = (float)mu;
    sig_out[row] = (float)sigma;
  }
}

// ---------------------------------------------------------------------------
// Kernel 2: per-batch tridiagonal solve via parallel cyclic reduction, f32.
// Round-13 structure (ping-pong, 1 barrier/step) with the R-array replaced
// by direct v_rcp_f32 on the neighbor B values (1-ulp, same f32-solve error
// class -- PCR precision demonstrably does not drive absmax: f64-PCR r12 and
// f32-PCR r13 both landed absmax 2048). Saves 8KB LDS + 3 LDS ops/step.
// ---------------------------------------------------------------------------
__global__ __launch_bounds__(1024) void pcr_solve_kernel(
    const float* __restrict__ mu, const float* __restrict__ sigma,
    const float* __restrict__ w_comp, float* __restrict__ out) {
  __shared__ float A[2][XLEN], B[2][XLEN], C[2][XLEN], D[2][XLEN];
  const int i = threadIdx.x;
  const int g = blockIdx.x * XLEN + i;

  const float w = w_comp[0];
  const float offf  = -2.0f * w;
  const float mainw = (i == 0 || i == XLEN - 1) ? (2.0f * w) : (4.0f * w);
  const float sr = 1.0f / sigma[g];      // f32, matches reference
  const float bf = mainw + sr;           // f32 diag entry
  const float df = mu[g] * sr;           // f32 rhs

  A[0][i] = (i == 0) ? 0.0f : offf;
  C[0][i] = (i == XLEN - 1) ? 0.0f : offf;
  B[0][i] = bf;
  D[0][i] = df;
  __syncthreads();

  int cur = 0;
  for (int s = 1; s < XLEN; s <<= 1) {
    const float ai = A[cur][i], bi = B[cur][i], ci = C[cur][i], di = D[cur][i];
    float am = 0.0f, cm = 0.0f, dm = 0.0f, rm = 0.0f;
    float ap = 0.0f, cp = 0.0f, dp = 0.0f, rp = 0.0f;
    if (i >= s) {
      am = A[cur][i - s]; cm = C[cur][i - s]; dm = D[cur][i - s];
      rm = HW_RCP(B[cur][i - s]);
    }
    if (i + s < XLEN) {
      ap = A[cur][i + s]; cp = C[cur][i + s]; dp = D[cur][i + s];
      rp = HW_RCP(B[cur][i + s]);
    }
    const float k1 = ai * rm;   // rm/rp are 0 when guarded out
    const float k2 = ci * rp;
    const float nb = bi - k1 * cm - k2 * ap;
    const float nd = di - k1 * dm - k2 * dp;
    const int nxt = cur ^ 1;
    A[nxt][i] = -k1 * am;
    C[nxt][i] = -k2 * cp;
    B[nxt][i] = nb;
    D[nxt][i] = nd;
    __syncthreads();
    cur = nxt;
  }

  out[g] = D[cur][i] / B[cur][i];
}

extern "C" void kernel_launch(void* const* d_in, const int* in_sizes, int n_in,
                              void* d_out, int out_size, void* d_ws, size_t ws_size,
                              hipStream_t stream) {
  const float* x      = (const float*)d_in[0];
  const float* w_comp = (const float*)d_in[1];
  float* out = (float*)d_out;

  float* mu_ws  = (float*)d_ws;
  float* sig_ws = mu_ws + ROWS;

  gaus_fit_kernel<<<ROWS / 16, 256, 0, stream>>>(x, mu_ws, sig_ws);
  pcr_solve_kernel<<<BN, XLEN, 0, stream>>>(mu_ws, sig_ws, w_comp, out);
}